// Round 1
// baseline (648.141 us; speedup 1.0000x reference)
//
#include <hip/hip_runtime.h>
#include <hip/hip_bf16.h>

#define N_NODE 100000
#define N_REL  8
#define EMB    32
#define OUT    32
#define N_BASIS 30
#define E_EDGE 1600000
#define BATCH  16384
#define H1 64
#define H2 32
#define H3 16
#define NEG_SLOPE 0.2f

// ---------------------------------------------------------------- K0: w = weight @ basis
__global__ __launch_bounds__(256) void k0_basis(const float* __restrict__ weight,
                                                const float* __restrict__ basis,
                                                float* __restrict__ w) {
    int i = blockIdx.x * 256 + threadIdx.x;          // 8 * 1024 = 8192 outputs
    if (i >= N_REL * EMB * OUT) return;
    int r = i >> 10, fo = i & 1023;
    float acc = 0.f;
    #pragma unroll
    for (int b = 0; b < N_BASIS; b++)
        acc = fmaf(weight[r * N_BASIS + b], basis[b * (EMB * OUT) + fo], acc);
    w[i] = acc;
}

// ------------------------------------- K1: xh = x@w, p_i/p_j = xh . att, agg = x@root + bias
__global__ __launch_bounds__(256) void k1_transform(const int* __restrict__ x_ids,
                                                    const float* __restrict__ emb,
                                                    const float* __restrict__ w,
                                                    const float* __restrict__ att,
                                                    const float* __restrict__ root,
                                                    const float* __restrict__ bias,
                                                    float* __restrict__ xh,
                                                    float* __restrict__ p_i,
                                                    float* __restrict__ p_j,
                                                    float* __restrict__ agg) {
    __shared__ float w_s[N_REL * EMB * OUT];   // 32 KB
    __shared__ float att_s[N_REL * 2 * OUT];   // 2 KB
    __shared__ float root_s[EMB * OUT];        // 4 KB
    __shared__ float bias_s[OUT];
    __shared__ float x_s[4 * EMB];

    const int t = threadIdx.x;
    for (int i = t; i < N_REL * EMB * OUT; i += 256) w_s[i] = w[i];
    for (int i = t; i < N_REL * 2 * OUT; i += 256) att_s[i] = att[i];
    for (int i = t; i < EMB * OUT; i += 256) root_s[i] = root[i];
    if (t < OUT) bias_s[t] = bias[t];
    __syncthreads();

    const int o = t & 31;          // output col
    const int r = t >> 5;          // relation
    const float a_i = att_s[r * 2 * OUT + o];
    const float a_j = att_s[r * 2 * OUT + OUT + o];

    for (int n0 = blockIdx.x * 4; n0 < N_NODE; n0 += gridDim.x * 4) {
        int nload = min(4, N_NODE - n0);
        if (t < nload * EMB) {
            int nn = t >> 5, f = t & 31;
            x_s[t] = emb[(long)x_ids[n0 + nn] * EMB + f];
        }
        __syncthreads();
        for (int u = 0; u < nload; u++) {
            int n = n0 + u;
            float acc = 0.f;
            #pragma unroll
            for (int f = 0; f < EMB; f++)
                acc = fmaf(x_s[u * EMB + f], w_s[(r * EMB + f) * OUT + o], acc);
            xh[((long)n * N_REL + r) * OUT + o] = acc;

            float pi = acc * a_i;
            float pj = acc * a_j;
            #pragma unroll
            for (int off = 16; off > 0; off >>= 1) {
                pi += __shfl_down(pi, off, 32);
                pj += __shfl_down(pj, off, 32);
            }
            if (o == 0) { p_i[n * N_REL + r] = pi; p_j[n * N_REL + r] = pj; }

            if (r == 0) {   // agg init = x@root + bias (one 32-lane group per node)
                float ra = bias_s[o];
                #pragma unroll
                for (int f = 0; f < EMB; f++)
                    ra = fmaf(x_s[u * EMB + f], root_s[f * OUT + o], ra);
                agg[(long)n * OUT + o] = ra;
            }
        }
        __syncthreads();
    }
}

// ---------------------------------------------------------------- K2: alpha + segment max
__global__ __launch_bounds__(256) void k2_alpha(const int* __restrict__ src,
                                                const int* __restrict__ dst,
                                                const int* __restrict__ et,
                                                const float* __restrict__ p_i,
                                                const float* __restrict__ p_j,
                                                float* __restrict__ alpha,
                                                unsigned* __restrict__ segmax) {
    int e = blockIdx.x * 256 + threadIdx.x;
    if (e >= E_EDGE) return;
    int s = src[e], d = dst[e], r = et[e];
    float a = p_i[d * N_REL + r] + p_j[s * N_REL + r];
    a = (a >= 0.f) ? a : NEG_SLOPE * a;
    alpha[e] = a;
    unsigned bits = __float_as_uint(a);
    unsigned key = (bits & 0x80000000u) ? ~bits : (bits | 0x80000000u);
    atomicMax(&segmax[d * N_REL + r], key);
}

// ---------------------------------------------------------------- K3: exp + segment sum
__global__ __launch_bounds__(256) void k3_exp(const int* __restrict__ dst,
                                              const int* __restrict__ et,
                                              const unsigned* __restrict__ segmax,
                                              float* __restrict__ alpha,
                                              float* __restrict__ denom) {
    int e = blockIdx.x * 256 + threadIdx.x;
    if (e >= E_EDGE) return;
    int seg = dst[e] * N_REL + et[e];
    unsigned key = segmax[seg];
    unsigned bits = (key & 0x80000000u) ? (key & 0x7FFFFFFFu) : ~key;
    float amax = __uint_as_float(bits);
    float ex = expf(alpha[e] - amax);
    alpha[e] = ex;                       // in-place: alpha now holds ex
    atomicAdd(&denom[seg], ex);
}

// ------------------------------------------- K4: agg[dst] += (ex/denom) * xh[src, et]
__global__ __launch_bounds__(256) void k4_scatter(const int* __restrict__ src,
                                                  const int* __restrict__ dst,
                                                  const int* __restrict__ et,
                                                  const float* __restrict__ ex,
                                                  const float* __restrict__ denom,
                                                  const float* __restrict__ xh,
                                                  float* __restrict__ agg) {
    long idx = (long)blockIdx.x * 256 + threadIdx.x;
    int e = (int)(idx >> 5);
    int o = (int)(idx & 31);
    if (e >= E_EDGE) return;
    int s = src[e], d = dst[e], r = et[e];
    float al = ex[e] / (denom[d * N_REL + r] + 1e-16f);
    float v = al * xh[((long)s * N_REL + r) * OUT + o];
    atomicAdd(&agg[(long)d * OUT + o], v);
}

// ---------------------------------------------------------------- K5: gather + MLP
__global__ __launch_bounds__(256) void k5_mlp(const int* __restrict__ users,
                                              const int* __restrict__ bundles,
                                              const float* __restrict__ agg,
                                              const float* __restrict__ W1,
                                              const float* __restrict__ b1,
                                              const float* __restrict__ W2,
                                              const float* __restrict__ b2,
                                              const float* __restrict__ W3,
                                              const float* __restrict__ b3,
                                              const float* __restrict__ Wo,
                                              const float* __restrict__ bo,
                                              float* __restrict__ out) {
    __shared__ float W1s[2 * OUT * H1], W2s[H1 * H2], W3s[H2 * H3], Wos[H3];
    __shared__ float b1s[H1], b2s[H2], b3s[H3];
    __shared__ float bos;
    int t = threadIdx.x;
    for (int i = t; i < 2 * OUT * H1; i += 256) W1s[i] = W1[i];
    for (int i = t; i < H1 * H2; i += 256) W2s[i] = W2[i];
    for (int i = t; i < H2 * H3; i += 256) W3s[i] = W3[i];
    if (t < H3) Wos[t] = Wo[t];
    if (t < H1) b1s[t] = b1[t];
    if (t < H2) b2s[t] = b2[t];
    if (t < H3) b3s[t] = b3[t];
    if (t == 0) bos = bo[0];
    __syncthreads();

    int wave = t >> 6;
    int l = t & 63;
    for (int b = blockIdx.x * 4 + wave; b < BATCH; b += gridDim.x * 4) {
        int u = users[b], v = bundles[b];
        float z = (l < 32) ? agg[(long)u * OUT + l] : agg[(long)v * OUT + (l - 32)];
        z = fmaxf(z, 0.f);                       // h = relu(agg) applied on gather

        float acc = b1s[l];
        for (int k = 0; k < 64; k++)
            acc = fmaf(__shfl(z, k, 64), W1s[k * H1 + l], acc);
        float h1 = fmaxf(acc, 0.f);

        int o2 = l & 31;
        acc = b2s[o2];
        for (int k = 0; k < 64; k++)
            acc = fmaf(__shfl(h1, k, 64), W2s[k * H2 + o2], acc);
        float h2 = fmaxf(acc, 0.f);

        int o3 = l & 15;
        acc = b3s[o3];
        for (int k = 0; k < 32; k++)
            acc = fmaf(__shfl(h2, k, 64), W3s[k * H3 + o3], acc);
        float h3 = fmaxf(acc, 0.f);

        float term = (l < 16) ? h3 * Wos[l] : 0.f;
        #pragma unroll
        for (int off = 8; off; off >>= 1) term += __shfl_down(term, off, 64);
        if (l == 0) out[b] = term + bos;
    }
}

extern "C" void kernel_launch(void* const* d_in, const int* in_sizes, int n_in,
                              void* d_out, int out_size, void* d_ws, size_t ws_size,
                              hipStream_t stream) {
    (void)in_sizes; (void)n_in; (void)out_size; (void)ws_size;
    const int*   x_ids  = (const int*)d_in[0];
    const int*   eidx   = (const int*)d_in[1];     // (2,E): row0=src, row1=dst
    const int*   etype  = (const int*)d_in[2];
    const int*   users  = (const int*)d_in[3];
    const int*   bund   = (const int*)d_in[4];
    const float* emb    = (const float*)d_in[5];
    const float* basis  = (const float*)d_in[6];
    const float* weight = (const float*)d_in[7];
    const float* att    = (const float*)d_in[8];
    const float* root   = (const float*)d_in[9];
    const float* bias   = (const float*)d_in[10];
    const float* W1 = (const float*)d_in[11]; const float* b1 = (const float*)d_in[12];
    const float* W2 = (const float*)d_in[13]; const float* b2 = (const float*)d_in[14];
    const float* W3 = (const float*)d_in[15]; const float* b3 = (const float*)d_in[16];
    const float* Wo = (const float*)d_in[17]; const float* bo = (const float*)d_in[18];
    float* out = (float*)d_out;

    const int* src = eidx;
    const int* dst = eidx + E_EDGE;

    // workspace layout (floats)
    float* ws     = (float*)d_ws;
    float* w      = ws;                                   //  8,192
    float* xh     = w + N_REL * EMB * OUT;                // 25,600,000
    float* p_i    = xh + (long)N_NODE * N_REL * OUT;      //    800,000
    float* p_j    = p_i + N_NODE * N_REL;                 //    800,000
    float* agg    = p_j + N_NODE * N_REL;                 //  3,200,000
    float* alpha  = agg + N_NODE * OUT;                   //  1,600,000
    float* denom  = alpha + E_EDGE;                       //    800,000
    unsigned* segmax = (unsigned*)(denom + N_NODE * N_REL); // 800,000 u32

    // zero-init denom + segmax (adjacent)
    hipMemsetAsync(denom, 0, (size_t)(N_NODE * N_REL) * 2 * sizeof(float), stream);

    k0_basis<<<(N_REL * EMB * OUT + 255) / 256, 256, 0, stream>>>(weight, basis, w);
    k1_transform<<<2048, 256, 0, stream>>>(x_ids, emb, w, att, root, bias,
                                           xh, p_i, p_j, agg);
    k2_alpha<<<(E_EDGE + 255) / 256, 256, 0, stream>>>(src, dst, etype, p_i, p_j,
                                                       alpha, segmax);
    k3_exp<<<(E_EDGE + 255) / 256, 256, 0, stream>>>(dst, etype, segmax, alpha, denom);
    k4_scatter<<<(int)(((long)E_EDGE * 32 + 255) / 256), 256, 0, stream>>>(
        src, dst, etype, alpha, denom, xh, agg);
    k5_mlp<<<512, 256, 0, stream>>>(users, bund, agg, W1, b1, W2, b2, W3, b3,
                                    Wo, bo, out);
}